// Round 1
// baseline (755.262 us; speedup 1.0000x reference)
//
#include <hip/hip_runtime.h>

#define NNODES 50000
#define NEDGES 800000
#define DIM 96
#define LLDIM 64
#define NGROUPS (NNODES / 8)   // 6250, exact

// Scatter-add h[dst] rows into agg[src] for edges matching `rel`.
// 32 lanes per edge, 3 floats per lane. Fire-and-forget f32 atomics.
__global__ void scatter_kernel(const int* __restrict__ ei, const int* __restrict__ et,
                               const float* __restrict__ h, float* __restrict__ agg,
                               float* __restrict__ cnt, int rel) {
    int e = blockIdx.x * 8 + (threadIdx.x >> 5);
    if (e >= NEDGES) return;
    if (et[e] != rel) return;
    int lane = threadIdx.x & 31;
    int src = ei[e];
    int dst = ei[NEDGES + e];
    const float* hrow = h + (size_t)dst * DIM;
    float* arow = agg + (size_t)src * DIM;
    atomicAdd(&arow[lane], hrow[lane]);
    atomicAdd(&arow[lane + 32], hrow[lane + 32]);
    atomicAdd(&arow[lane + 64], hrow[lane + 64]);
    if (lane == 0) atomicAdd(&cnt[src], 1.0f);
}

// h_next[n,c] = relu( (agg[n,:]@W[:,c]) / max(cnt[n],1) + h[n,:]@R[:,c] + b[c] )
// Thread: c = tid%96, 8 nodes per thread. W/R reads are wave-coalesced and
// L1/L2-resident (36KB each); agg/h row reads are wave-uniform broadcasts.
__global__ void layer_kernel(const float* __restrict__ h, const float* __restrict__ agg,
                             const float* __restrict__ cnt, const float* __restrict__ W,
                             const float* __restrict__ R, const float* __restrict__ b,
                             float* __restrict__ out) {
    int tid = blockIdx.x * blockDim.x + threadIdx.x;
    int c = tid % DIM;
    int g = tid / DIM;
    if (g >= NGROUPS) return;
    int n0 = g * 8;

    float acc_a[8], acc_r[8];
#pragma unroll
    for (int j = 0; j < 8; ++j) { acc_a[j] = 0.0f; acc_r[j] = 0.0f; }

    const float* aggb = agg + (size_t)n0 * DIM;
    const float* hb = h + (size_t)n0 * DIM;

    for (int k = 0; k < DIM; k += 4) {
        float w0 = W[(k + 0) * DIM + c];
        float w1 = W[(k + 1) * DIM + c];
        float w2 = W[(k + 2) * DIM + c];
        float w3 = W[(k + 3) * DIM + c];
        float r0 = R[(k + 0) * DIM + c];
        float r1 = R[(k + 1) * DIM + c];
        float r2 = R[(k + 2) * DIM + c];
        float r3 = R[(k + 3) * DIM + c];
#pragma unroll
        for (int j = 0; j < 8; ++j) {
            float4 av = *(const float4*)(aggb + (size_t)j * DIM + k);
            float4 hv = *(const float4*)(hb + (size_t)j * DIM + k);
            acc_a[j] += av.x * w0 + av.y * w1 + av.z * w2 + av.w * w3;
            acc_r[j] += hv.x * r0 + hv.y * r1 + hv.z * r2 + hv.w * r3;
        }
    }

    float bc = b[c];
#pragma unroll
    for (int j = 0; j < 8; ++j) {
        float s = 1.0f / fmaxf(cnt[n0 + j], 1.0f);
        float v = acc_a[j] * s + acc_r[j] + bc;
        out[(size_t)(n0 + j) * DIM + c] = fmaxf(v, 0.0f);
    }
}

// out[n,c] = h[n,:] @ lin_w[:,c] + lin_b[c]   (c in [0,64))
__global__ void final_kernel(const float* __restrict__ h, const float* __restrict__ LW,
                             const float* __restrict__ LB, float* __restrict__ out) {
    int tid = blockIdx.x * blockDim.x + threadIdx.x;
    int c = tid % LLDIM;
    int g = tid / LLDIM;
    if (g >= NGROUPS) return;
    int n0 = g * 8;

    float acc[8];
#pragma unroll
    for (int j = 0; j < 8; ++j) acc[j] = 0.0f;

    const float* hb = h + (size_t)n0 * DIM;

    for (int k = 0; k < DIM; k += 4) {
        float w0 = LW[(k + 0) * LLDIM + c];
        float w1 = LW[(k + 1) * LLDIM + c];
        float w2 = LW[(k + 2) * LLDIM + c];
        float w3 = LW[(k + 3) * LLDIM + c];
#pragma unroll
        for (int j = 0; j < 8; ++j) {
            float4 hv = *(const float4*)(hb + (size_t)j * DIM + k);
            acc[j] += hv.x * w0 + hv.y * w1 + hv.z * w2 + hv.w * w3;
        }
    }

    float bc = LB[c];
#pragma unroll
    for (int j = 0; j < 8; ++j) {
        out[(size_t)(n0 + j) * LLDIM + c] = acc[j] + bc;
    }
}

extern "C" void kernel_launch(void* const* d_in, const int* in_sizes, int n_in,
                              void* d_out, int out_size, void* d_ws, size_t ws_size,
                              hipStream_t stream) {
    const float* x     = (const float*)d_in[0];
    const int*   ei    = (const int*)d_in[1];
    const int*   et    = (const int*)d_in[2];
    const float* w1    = (const float*)d_in[3];
    const float* root1 = (const float*)d_in[4];
    const float* b1    = (const float*)d_in[5];
    const float* w2    = (const float*)d_in[6];
    const float* root2 = (const float*)d_in[7];
    const float* b2    = (const float*)d_in[8];
    const float* lin_w = (const float*)d_in[9];
    const float* lin_b = (const float*)d_in[10];

    float* bufA = (float*)d_ws;                 // N*96
    float* bufB = bufA + (size_t)NNODES * DIM;  // N*96
    float* agg  = bufB + (size_t)NNODES * DIM;  // N*96
    float* cnt  = agg + (size_t)NNODES * DIM;   // N   (contiguous after agg)

    const int scatter_blocks = (NEDGES + 7) / 8;          // 8 edges/block of 256
    const int layer_blocks   = (NGROUPS * DIM + 255) / 256;
    const int final_blocks   = (NGROUPS * LLDIM + 255) / 256;
    const size_t zero_bytes  = ((size_t)NNODES * DIM + NNODES) * sizeof(float);

    // Layer 0: rel=0, W=w1[0], root1, b1.  x -> bufA
    hipMemsetAsync(agg, 0, zero_bytes, stream);
    scatter_kernel<<<scatter_blocks, 256, 0, stream>>>(ei, et, x, agg, cnt, 0);
    layer_kernel<<<layer_blocks, 256, 0, stream>>>(x, agg, cnt, w1, root1, b1, bufA);

    // Layer 1: rel=1, W=w2[1], root2, b2.  bufA -> bufB
    hipMemsetAsync(agg, 0, zero_bytes, stream);
    scatter_kernel<<<scatter_blocks, 256, 0, stream>>>(ei, et, bufA, agg, cnt, 1);
    layer_kernel<<<layer_blocks, 256, 0, stream>>>(bufA, agg, cnt, w2 + (size_t)1 * DIM * DIM,
                                                   root2, b2, bufB);

    // Layer 2: rel=2, W=w2[2], root2, b2.  bufB -> bufA
    hipMemsetAsync(agg, 0, zero_bytes, stream);
    scatter_kernel<<<scatter_blocks, 256, 0, stream>>>(ei, et, bufB, agg, cnt, 2);
    layer_kernel<<<layer_blocks, 256, 0, stream>>>(bufB, agg, cnt, w2 + (size_t)2 * DIM * DIM,
                                                   root2, b2, bufA);

    // Final linear: bufA -> d_out
    final_kernel<<<final_blocks, 256, 0, stream>>>(bufA, lin_w, lin_b, (float*)d_out);
}

// Round 2
// 329.255 us; speedup vs baseline: 2.2939x; 2.2939x over previous
//
#include <hip/hip_runtime.h>

#define NNODES 50000
#define NEDGES 800000
#define DIM 96
#define LLDIM 64
#define NRELS 3            // metapath relations 0,1,2
#define SCAN_N (NRELS * NNODES)

// ---------------- CSR build ----------------

__global__ void hist_kernel(const int* __restrict__ ei, const int* __restrict__ et,
                            int* __restrict__ deg) {
    int e = blockIdx.x * 256 + threadIdx.x;
    if (e >= NEDGES) return;
    int r = et[e];
    if (r < NRELS) atomicAdd(&deg[r * NNODES + ei[e]], 1);
}

// block-local exclusive scan over 1024 items (256 thr x 4), block totals to partials
__global__ void scan1_kernel(const int* __restrict__ in, int* __restrict__ out,
                             int* __restrict__ partials, int n) {
    __shared__ int sdata[256];
    int tid = threadIdx.x;
    int base = blockIdx.x * 1024 + tid * 4;
    int v0 = (base + 0 < n) ? in[base + 0] : 0;
    int v1 = (base + 1 < n) ? in[base + 1] : 0;
    int v2 = (base + 2 < n) ? in[base + 2] : 0;
    int v3 = (base + 3 < n) ? in[base + 3] : 0;
    int tsum = v0 + v1 + v2 + v3;
    sdata[tid] = tsum;
    __syncthreads();
    for (int off = 1; off < 256; off <<= 1) {
        int x = sdata[tid];
        int y = (tid >= off) ? sdata[tid - off] : 0;
        __syncthreads();
        sdata[tid] = x + y;
        __syncthreads();
    }
    int excl = sdata[tid] - tsum;
    if (tid == 255) partials[blockIdx.x] = sdata[255];
    if (base + 0 < n) out[base + 0] = excl;
    excl += v0;
    if (base + 1 < n) out[base + 1] = excl;
    excl += v1;
    if (base + 2 < n) out[base + 2] = excl;
    excl += v2;
    if (base + 3 < n) out[base + 3] = excl;
}

__global__ void scan2_kernel(int* __restrict__ partials, int nb) {
    __shared__ int sdata[256];
    int tid = threadIdx.x;
    int v = (tid < nb) ? partials[tid] : 0;
    sdata[tid] = v;
    __syncthreads();
    for (int off = 1; off < 256; off <<= 1) {
        int x = sdata[tid];
        int y = (tid >= off) ? sdata[tid - off] : 0;
        __syncthreads();
        sdata[tid] = x + y;
        __syncthreads();
    }
    partials[tid] = sdata[tid] - v;   // exclusive
}

__global__ void scan3_kernel(int* __restrict__ out, const int* __restrict__ partials, int n) {
    int idx = blockIdx.x * 256 + threadIdx.x;
    if (idx < n) out[idx] += partials[idx >> 10];
}

// cursor (row_end) pre-initialized to row_start; after fill it holds row ends.
__global__ void fill_kernel(const int* __restrict__ ei, const int* __restrict__ et,
                            int* __restrict__ cursor, int* __restrict__ col) {
    int e = blockIdx.x * 256 + threadIdx.x;
    if (e >= NEDGES) return;
    int r = et[e];
    if (r < NRELS) {
        int pos = atomicAdd(&cursor[r * NNODES + ei[e]], 1);
        col[pos] = ei[NEDGES + e];
    }
}

// ---------------- per-layer aggregate (gather, mean folded in) ----------------

__global__ void gather_kernel(const float* __restrict__ h, const int* __restrict__ row_start,
                              const int* __restrict__ row_end, const int* __restrict__ col,
                              float* __restrict__ agg, int rel) {
    int g = blockIdx.x * 8 + (threadIdx.x >> 5);   // node id
    if (g >= NNODES) return;
    int lane = threadIdx.x & 31;
    int s = row_start[rel * NNODES + g];
    int e = row_end[rel * NNODES + g];
    float a0 = 0.0f, a1 = 0.0f, a2 = 0.0f;
    for (int i = s; i < e; ++i) {
        int d = col[i];
        const float* hr = h + (size_t)d * DIM;
        a0 += hr[lane];
        a1 += hr[lane + 32];
        a2 += hr[lane + 64];
    }
    float scl = 1.0f / fmaxf((float)(e - s), 1.0f);
    float* ar = agg + (size_t)g * DIM;
    ar[lane] = a0 * scl;
    ar[lane + 32] = a1 * scl;
    ar[lane + 64] = a2 * scl;
}

// ---------------- layer GEMM: out = relu(agg@W + h@R + b) ----------------
// Block: 64 nodes x 96 cols, 384 threads. K = 2*96 in 6 chunks of 32.
// agg is pre-scaled by 1/max(cnt,1) in gather_kernel.

__global__ __launch_bounds__(384) void layer_kernel(
    const float* __restrict__ h, const float* __restrict__ agg,
    const float* __restrict__ W, const float* __restrict__ R,
    const float* __restrict__ b, float* __restrict__ out) {
    __shared__ __align__(16) float Alds[32][68];   // [k][node], pad to 68
    __shared__ __align__(16) float Wlds[32][96];   // [k][col]
    int tid = threadIdx.x;
    int q = tid % 24;        // col quad: cols 4q..4q+3
    int nb = tid / 24;       // 0..15: nodes nb*4..nb*4+3
    int n0 = blockIdx.x * 64;

    float acc[4][4];
#pragma unroll
    for (int j = 0; j < 4; ++j)
#pragma unroll
        for (int c = 0; c < 4; ++c) acc[j][c] = 0.0f;

    for (int chunk = 0; chunk < 6; ++chunk) {
        const float* Aptr = (chunk < 3) ? agg : h;
        const float* Bptr = (chunk < 3) ? W : R;
        int kc = (chunk % 3) * 32;
        __syncthreads();
        // stage A chunk: 64 nodes x 32 k, transposed to [k][node]
        for (int idx = tid; idx < 512; idx += 384) {
            int row = idx >> 3;            // node 0..63
            int kq = idx & 7;              // float4 index in k
            int rnode = n0 + row;
            if (rnode >= NNODES) rnode = NNODES - 1;   // clamp (guarded at store)
            float4 v = *(const float4*)(Aptr + (size_t)rnode * DIM + kc + kq * 4);
            int kk = kq * 4;
            Alds[kk + 0][row] = v.x;
            Alds[kk + 1][row] = v.y;
            Alds[kk + 2][row] = v.z;
            Alds[kk + 3][row] = v.w;
        }
        // stage W chunk: 32 k x 96 cols
        for (int idx = tid; idx < 768; idx += 384) {
            int kr = idx / 24;
            int cq = idx % 24;
            *(float4*)&Wlds[kr][cq * 4] =
                *(const float4*)(Bptr + (size_t)(kc + kr) * DIM + cq * 4);
        }
        __syncthreads();
#pragma unroll 8
        for (int k = 0; k < 32; ++k) {
            float4 w4 = *(float4*)&Wlds[k][q * 4];
            float4 a4 = *(float4*)&Alds[k][nb * 4];
            acc[0][0] += a4.x * w4.x; acc[0][1] += a4.x * w4.y;
            acc[0][2] += a4.x * w4.z; acc[0][3] += a4.x * w4.w;
            acc[1][0] += a4.y * w4.x; acc[1][1] += a4.y * w4.y;
            acc[1][2] += a4.y * w4.z; acc[1][3] += a4.y * w4.w;
            acc[2][0] += a4.z * w4.x; acc[2][1] += a4.z * w4.y;
            acc[2][2] += a4.z * w4.z; acc[2][3] += a4.z * w4.w;
            acc[3][0] += a4.w * w4.x; acc[3][1] += a4.w * w4.y;
            acc[3][2] += a4.w * w4.z; acc[3][3] += a4.w * w4.w;
        }
    }

    float4 bv = *(const float4*)(b + q * 4);
    int nbase = n0 + nb * 4;
#pragma unroll
    for (int j = 0; j < 4; ++j) {
        int n = nbase + j;
        if (n < NNODES) {
            float4 r;
            r.x = fmaxf(acc[j][0] + bv.x, 0.0f);
            r.y = fmaxf(acc[j][1] + bv.y, 0.0f);
            r.z = fmaxf(acc[j][2] + bv.z, 0.0f);
            r.w = fmaxf(acc[j][3] + bv.w, 0.0f);
            *(float4*)(out + (size_t)n * DIM + q * 4) = r;
        }
    }
}

// ---------------- final linear: out = h @ lin_w + lin_b (no relu) ----------------
// Block: 64 nodes x 64 cols, 256 threads. K = 96 in 3 chunks of 32.

__global__ __launch_bounds__(256) void final_kernel(
    const float* __restrict__ h, const float* __restrict__ LW,
    const float* __restrict__ LB, float* __restrict__ out) {
    __shared__ __align__(16) float Alds[32][68];
    __shared__ __align__(16) float Wlds[32][LLDIM];
    int tid = threadIdx.x;
    int q = tid % 16;        // col quad
    int nb = tid / 16;       // 0..15
    int n0 = blockIdx.x * 64;

    float acc[4][4];
#pragma unroll
    for (int j = 0; j < 4; ++j)
#pragma unroll
        for (int c = 0; c < 4; ++c) acc[j][c] = 0.0f;

    for (int chunk = 0; chunk < 3; ++chunk) {
        int kc = chunk * 32;
        __syncthreads();
        for (int idx = tid; idx < 512; idx += 256) {
            int row = idx >> 3;
            int kq = idx & 7;
            int rnode = n0 + row;
            if (rnode >= NNODES) rnode = NNODES - 1;
            float4 v = *(const float4*)(h + (size_t)rnode * DIM + kc + kq * 4);
            int kk = kq * 4;
            Alds[kk + 0][row] = v.x;
            Alds[kk + 1][row] = v.y;
            Alds[kk + 2][row] = v.z;
            Alds[kk + 3][row] = v.w;
        }
        for (int idx = tid; idx < 512; idx += 256) {
            int kr = idx / 16;
            int cq = idx % 16;
            *(float4*)&Wlds[kr][cq * 4] =
                *(const float4*)(LW + (size_t)(kc + kr) * LLDIM + cq * 4);
        }
        __syncthreads();
#pragma unroll 8
        for (int k = 0; k < 32; ++k) {
            float4 w4 = *(float4*)&Wlds[k][q * 4];
            float4 a4 = *(float4*)&Alds[k][nb * 4];
            acc[0][0] += a4.x * w4.x; acc[0][1] += a4.x * w4.y;
            acc[0][2] += a4.x * w4.z; acc[0][3] += a4.x * w4.w;
            acc[1][0] += a4.y * w4.x; acc[1][1] += a4.y * w4.y;
            acc[1][2] += a4.y * w4.z; acc[1][3] += a4.y * w4.w;
            acc[2][0] += a4.z * w4.x; acc[2][1] += a4.z * w4.y;
            acc[2][2] += a4.z * w4.z; acc[2][3] += a4.z * w4.w;
            acc[3][0] += a4.w * w4.x; acc[3][1] += a4.w * w4.y;
            acc[3][2] += a4.w * w4.z; acc[3][3] += a4.w * w4.w;
        }
    }

    float4 bv = *(const float4*)(LB + q * 4);
    int nbase = n0 + nb * 4;
#pragma unroll
    for (int j = 0; j < 4; ++j) {
        int n = nbase + j;
        if (n < NNODES) {
            float4 r;
            r.x = acc[j][0] + bv.x;
            r.y = acc[j][1] + bv.y;
            r.z = acc[j][2] + bv.z;
            r.w = acc[j][3] + bv.w;
            *(float4*)(out + (size_t)n * LLDIM + q * 4) = r;
        }
    }
}

extern "C" void kernel_launch(void* const* d_in, const int* in_sizes, int n_in,
                              void* d_out, int out_size, void* d_ws, size_t ws_size,
                              hipStream_t stream) {
    const float* x     = (const float*)d_in[0];
    const int*   ei    = (const int*)d_in[1];
    const int*   et    = (const int*)d_in[2];
    const float* w1    = (const float*)d_in[3];
    const float* root1 = (const float*)d_in[4];
    const float* b1    = (const float*)d_in[5];
    const float* w2    = (const float*)d_in[6];
    const float* root2 = (const float*)d_in[7];
    const float* b2    = (const float*)d_in[8];
    const float* lin_w = (const float*)d_in[9];
    const float* lin_b = (const float*)d_in[10];

    float* bufA = (float*)d_ws;                      // N*96
    float* bufB = bufA + (size_t)NNODES * DIM;       // N*96
    float* agg  = bufB + (size_t)NNODES * DIM;       // N*96
    int* deg       = (int*)(agg + (size_t)NNODES * DIM);
    int* row_start = deg + SCAN_N;
    int* row_end   = row_start + SCAN_N;
    int* col       = row_end + SCAN_N;               // up to NEDGES
    int* partials  = col + NEDGES;                   // 256

    const int edge_blocks = (NEDGES + 255) / 256;
    const int scan_blocks = (SCAN_N + 1023) / 1024;  // 147
    const int node_tiles  = (NNODES + 63) / 64;      // 782
    const int gath_blocks = (NNODES + 7) / 8;        // 6250

    // ---- CSR build (edge structure is identical for all 3 layers) ----
    hipMemsetAsync(deg, 0, SCAN_N * sizeof(int), stream);
    hist_kernel<<<edge_blocks, 256, 0, stream>>>(ei, et, deg);
    scan1_kernel<<<scan_blocks, 256, 0, stream>>>(deg, row_start, partials, SCAN_N);
    scan2_kernel<<<1, 256, 0, stream>>>(partials, scan_blocks);
    scan3_kernel<<<(SCAN_N + 255) / 256, 256, 0, stream>>>(row_start, partials, SCAN_N);
    hipMemcpyAsync(row_end, row_start, SCAN_N * sizeof(int), hipMemcpyDeviceToDevice, stream);
    fill_kernel<<<edge_blocks, 256, 0, stream>>>(ei, et, row_end, col);

    // ---- Layer 0: rel 0, w1[0], root1, b1 :  x -> bufA ----
    gather_kernel<<<gath_blocks, 256, 0, stream>>>(x, row_start, row_end, col, agg, 0);
    layer_kernel<<<node_tiles, 384, 0, stream>>>(x, agg, w1, root1, b1, bufA);

    // ---- Layer 1: rel 1, w2[1], root2, b2 :  bufA -> bufB ----
    gather_kernel<<<gath_blocks, 256, 0, stream>>>(bufA, row_start, row_end, col, agg, 1);
    layer_kernel<<<node_tiles, 384, 0, stream>>>(bufA, agg, w2 + (size_t)1 * DIM * DIM,
                                                 root2, b2, bufB);

    // ---- Layer 2: rel 2, w2[2], root2, b2 :  bufB -> bufA ----
    gather_kernel<<<gath_blocks, 256, 0, stream>>>(bufB, row_start, row_end, col, agg, 2);
    layer_kernel<<<node_tiles, 384, 0, stream>>>(bufB, agg, w2 + (size_t)2 * DIM * DIM,
                                                 root2, b2, bufA);

    // ---- Final linear: bufA -> d_out ----
    final_kernel<<<node_tiles, 256, 0, stream>>>(bufA, lin_w, lin_b, (float*)d_out);
}